// Round 2
// baseline (74068.872 us; speedup 1.0000x reference)
//
#include <hip/hip_runtime.h>
#include <math.h>

typedef float v4 __attribute__((ext_vector_type(4)));

#define NB 256
#define LATD 128
#define UPS 64
#define H 512
#define V 25
#define TS 500
#define EGI_STRIDE 32
#define LGS 32
#define NBLK 256
#define NGRP 16
#define GSZ (NBLK / NGRP)

#define OFF_HB      0
#define OFF_UCTX    (OFF_HB + 2 * NB * H)
#define OFF_EGI     (OFF_UCTX + NB * UPS)
#define OFF_WFOLD   (OFF_EGI + 3 * H * EGI_STRIDE)
#define OFF_BCAT2   (OFF_WFOLD + H * UPS)
#define OFF_WOUTT   (OFF_BCAT2 + H)
#define OFF_WMEMT   (OFF_WOUTT + H * LGS)
#define OFF_LG      (OFF_WMEMT + UPS * H)
#define OFF_BAR     (OFF_LG + 2 * NB * LGS)

__global__ void k_init_egi(const float* __restrict__ embed, const float* __restrict__ W_ih,
                           const float* __restrict__ b_ih, float* __restrict__ EgiT) {
    int idx = blockIdx.x * 256 + threadIdx.x;
    if (idx >= V * 3 * H) return;
    int v = idx % V, n = idx / V;
    const float* e = embed + (size_t)v * H;
    const float* wr = W_ih + (size_t)n * H;
    float acc = b_ih[n];
    for (int k = 0; k < H; ++k) acc += e[k] * wr[k];
    EgiT[n * EGI_STRIDE + v] = acc;
}

__global__ void k_init_h0(const float* __restrict__ latent, const float* __restrict__ W_hid,
                          const float* __restrict__ b_hid, float* __restrict__ hB) {
    int bb = blockIdx.x, jj = threadIdx.x;
    const float* l = latent + (size_t)bb * LATD;
    const float* wr = W_hid + (size_t)jj * LATD;
    float acc = b_hid[jj];
    for (int k = 0; k < LATD; ++k) acc += l[k] * wr[k];
    hB[(size_t)bb * H + jj] = acc;
}

__global__ void k_init_fold(const float* __restrict__ W_cat, const float* __restrict__ W_mem,
                            float* __restrict__ Wfold) {
    int idx = blockIdx.x * 256 + threadIdx.x;
    if (idx >= H * UPS) return;
    int u = idx & 63, jj = idx >> 6;
    float acc = 0.f;
    for (int k = 0; k < H; ++k)
        acc += W_cat[(size_t)jj * (2 * H) + H + k] * W_mem[(size_t)k * UPS + u];
    Wfold[(size_t)jj * UPS + u] = acc;
}

__global__ void k_init_bcat(const float* __restrict__ W_cat, const float* __restrict__ b_mem,
                            const float* __restrict__ b_cat, float* __restrict__ bcat2) {
    int jj = blockIdx.x * 256 + threadIdx.x;
    if (jj >= H) return;
    float acc = b_cat[jj];
    for (int k = 0; k < H; ++k) acc += W_cat[(size_t)jj * (2 * H) + H + k] * b_mem[k];
    bcat2[jj] = acc;
}

__global__ void k_init_woutT(const float* __restrict__ W_out, float* __restrict__ WoutT) {
    int idx = blockIdx.x * 256 + threadIdx.x;
    if (idx >= H * LGS) return;
    int jj = idx >> 5, v = idx & 31;
    WoutT[idx] = (v < V) ? W_out[(size_t)v * H + jj] : 0.f;
}

__global__ void k_init_wmemT(const float* __restrict__ W_mem, float* __restrict__ WmemT) {
    int idx = blockIdx.x * 256 + threadIdx.x;
    if (idx >= UPS * H) return;
    int u = idx >> 9, k = idx & 511;
    WmemT[idx] = W_mem[(size_t)k * UPS + u];
}

__global__ void k_init_bar(int* __restrict__ bar) {
    int i = threadIdx.x;
    if (i < NGRP * 32 + 64) bar[i] = 0;
}

__device__ __forceinline__ void grid_barrier(int* bar, int epoch) {
    __syncthreads();
    if (threadIdx.x == 0) {
        int* gcnt = bar + (blockIdx.x & (NGRP - 1)) * 32;
        int* root = bar + NGRP * 32;
        int* gen  = bar + NGRP * 32 + 32;
        int a = __hip_atomic_fetch_add(gcnt, 1, __ATOMIC_RELEASE, __HIP_MEMORY_SCOPE_AGENT);
        if (a == epoch * GSZ + (GSZ - 1)) {
            int r = __hip_atomic_fetch_add(root, 1, __ATOMIC_ACQ_REL, __HIP_MEMORY_SCOPE_AGENT);
            if (r == epoch * NGRP + (NGRP - 1))
                __hip_atomic_store(gen, epoch + 1, __ATOMIC_RELEASE, __HIP_MEMORY_SCOPE_AGENT);
        }
        while (__hip_atomic_load(gen, __ATOMIC_ACQUIRE, __HIP_MEMORY_SCOPE_AGENT) <= epoch)
            __builtin_amdgcn_s_sleep(1);
    }
    __syncthreads();
}

__global__ __launch_bounds__(512, 4) void k_main(
    const float* __restrict__ up, const float* __restrict__ W_hh,
    const float* __restrict__ b_hh, const float* __restrict__ W_cat,
    const float* __restrict__ b_out, float* __restrict__ out,
    float* __restrict__ hB, float* __restrict__ uctxB,
    const float* __restrict__ EgiT, const float* __restrict__ Wfold,
    const float* __restrict__ bcat2, const float* __restrict__ WoutT,
    const float* __restrict__ WmemT, float* __restrict__ logitsB,
    int* __restrict__ bar)
{
    const int tid = threadIdx.x;
    const int bid = blockIdx.x;
    const int lane = tid & 63, w = tid >> 6;
    const int bq = bid & 3, jb = bid >> 2;
    const int b = bq * 64 + lane;
    const int j = __builtin_amdgcn_readfirstlane(jb * 8 + w);

    __shared__ float s_stage[64][9];
    __shared__ float s_lg[64][26];
    __shared__ float s_hp[64];
    __shared__ float s_ctx[8][64];
    __shared__ float s_mw[8], s_Sw[8];

    int ep = 0;

    for (int t = 0; t < TS; ++t) {
        const float* hc = hB + (size_t)(t & 1) * (NB * H);
        float* hn = hB + (size_t)((t + 1) & 1) * (NB * H);
        const float* lgprev = logitsB + ((t + 1) & 1) * (NB * LGS);
        float* lgcur = logitsB + (t & 1) * (NB * LGS);

        // ================= P1 =================
        int id = 0;
        if (t > 0) {
            const float* lr = lgprev + b * LGS;
            float best = lr[0];
            for (int v = 1; v < V; ++v) {
                float x = lr[v];
                if (x > best) { best = x; id = v; }
            }
        }
        if (jb == 0 && t > 0) {
            const float* lr2 = lgprev + b * LGS;
            for (int v = w; v < V; v += 8)
                out[((size_t)b * V + v) * TS + (t - 1)] = lr2[v];
        }
        if (jb == 1) {  // init logits accumulator with b_out bias
            float* dst = lgcur + bq * 64 * LGS;
            for (int i = tid; i < 64 * LGS; i += 512) {
                int v = i & 31;
                dst[i] = (v < V) ? b_out[v] : 0.f;
            }
        }
        {
            const v4* h4  = (const v4*)(hc + (size_t)b * H);
            const v4* wr4 = (const v4*)(W_hh + (size_t)j * H);
            const v4* wz4 = (const v4*)(W_hh + (size_t)(H + j) * H);
            const v4* wn4 = (const v4*)(W_hh + (size_t)(2 * H + j) * H);
            float ar = 0.f, az = 0.f, an = 0.f;
#pragma unroll 4
            for (int i = 0; i < H / 4; ++i) {
                v4 hv = h4[i];
                v4 wa = wr4[i], wb = wz4[i], wc = wn4[i];
                ar += hv.x * wa.x + hv.y * wa.y + hv.z * wa.z + hv.w * wa.w;
                az += hv.x * wb.x + hv.y * wb.y + hv.z * wb.z + hv.w * wb.w;
                an += hv.x * wc.x + hv.y * wc.y + hv.z * wc.z + hv.w * wc.w;
            }
            float gir = EgiT[j * EGI_STRIDE + id];
            float giz = EgiT[(H + j) * EGI_STRIDE + id];
            float gin = EgiT[(2 * H + j) * EGI_STRIDE + id];
            float sr = ar + b_hh[j] + gir;
            float sz = az + b_hh[H + j] + giz;
            float sn = an + b_hh[2 * H + j];
            float r = 1.f / (1.f + __expf(-sr));
            float z = 1.f / (1.f + __expf(-sz));
            float n = tanhf(gin + r * sn);
            float hold = hc[(size_t)b * H + j];
            s_stage[lane][w] = (1.f - z) * n + z * hold;
        }
        __syncthreads();
        hn[(size_t)(bq * 64 + (tid >> 3)) * H + jb * 8 + (tid & 7)] =
            s_stage[tid >> 3][tid & 7];
        grid_barrier(bar, ep++);

        // ================= P2 =================
        {
            const int b2 = bid;
            const float* hrow = hn + (size_t)b2 * H;
            const int uw = w * 8 + (lane >> 3);
            const int kc = (lane & 7) * 64;
            {
                const v4* hh4 = (const v4*)(hrow + kc);
                const v4* wm4 = (const v4*)(WmemT + (size_t)uw * H + kc);
                float a = 0.f;
#pragma unroll 4
                for (int i = 0; i < 16; ++i) {
                    v4 x = hh4[i], y = wm4[i];
                    a += x.x * y.x + x.y * y.y + x.z * y.z + x.w * y.w;
                }
                a += __shfl_xor(a, 1); a += __shfl_xor(a, 2); a += __shfl_xor(a, 4);
                if ((lane & 7) == 0) s_hp[uw] = a;
            }
            __syncthreads();
            const int u0 = (lane & 7) * 8;
            const int tsub = lane >> 3;
            v4 hpA = *(const v4*)&s_hp[u0];
            v4 hpB = *(const v4*)&s_hp[u0 + 4];
            float m = -1e30f, S = 0.f;
            float cx[8] = {0.f, 0.f, 0.f, 0.f, 0.f, 0.f, 0.f, 0.f};
#pragma unroll
            for (int p = 0; p < 8; ++p) {
                int tt = p * 64 + w * 8 + tsub;
                v4 ua = {0.f, 0.f, 0.f, 0.f}, ub = {0.f, 0.f, 0.f, 0.f};
                float part = 0.f;
                if (tt < TS) {
                    const v4* ur = (const v4*)(up + ((size_t)b2 * TS + tt) * UPS + u0);
                    ua = __builtin_nontemporal_load(ur);
                    ub = __builtin_nontemporal_load(ur + 1);
                    part = ua.x * hpA.x + ua.y * hpA.y + ua.z * hpA.z + ua.w * hpA.w
                         + ub.x * hpB.x + ub.y * hpB.y + ub.z * hpB.z + ub.w * hpB.w;
                }
                part += __shfl_xor(part, 1);
                part += __shfl_xor(part, 2);
                part += __shfl_xor(part, 4);
                float s = (tt < TS) ? part : -1e30f;
                float M = s;
                M = fmaxf(M, __shfl_xor(M, 8));
                M = fmaxf(M, __shfl_xor(M, 16));
                M = fmaxf(M, __shfl_xor(M, 32));
                float mn = fmaxf(m, M);
                float alpha = __expf(m - mn);
                float e = __expf(s - mn);
                float E = e;
                E += __shfl_xor(E, 8); E += __shfl_xor(E, 16); E += __shfl_xor(E, 32);
                S = S * alpha + E;
                m = mn;
#pragma unroll
                for (int i = 0; i < 4; ++i) cx[i] = cx[i] * alpha + e * ua[i];
#pragma unroll
                for (int i = 0; i < 4; ++i) cx[4 + i] = cx[4 + i] * alpha + e * ub[i];
            }
#pragma unroll
            for (int i = 0; i < 8; ++i) {
                cx[i] += __shfl_xor(cx[i], 8);
                cx[i] += __shfl_xor(cx[i], 16);
                cx[i] += __shfl_xor(cx[i], 32);
            }
            if (tsub == 0) {
#pragma unroll
                for (int i = 0; i < 8; ++i) s_ctx[w][u0 + i] = cx[i];
            }
            if (lane == 0) { s_mw[w] = m; s_Sw[w] = S; }
            __syncthreads();
            if (tid < UPS) {
                float M = s_mw[0];
                for (int i = 1; i < 8; ++i) M = fmaxf(M, s_mw[i]);
                float Sg = 0.f, c = 0.f;
                for (int i = 0; i < 8; ++i) {
                    float f = __expf(s_mw[i] - M);
                    Sg += s_Sw[i] * f;
                    c += s_ctx[i][tid] * f;
                }
                uctxB[(size_t)b2 * UPS + tid] = c / Sg;
            }
        }
        grid_barrier(bar, ep++);

        // ================= P3 =================
        {
            const v4* h4  = (const v4*)(hn + (size_t)b * H);
            const v4* wc4 = (const v4*)(W_cat + (size_t)j * (2 * H));
            float acc = 0.f;
#pragma unroll 4
            for (int i = 0; i < H / 4; ++i) {
                v4 hv = h4[i], wv = wc4[i];
                acc += hv.x * wv.x + hv.y * wv.y + hv.z * wv.z + hv.w * wv.w;
            }
            const v4* u4  = (const v4*)(uctxB + (size_t)b * UPS);
            const v4* wf4 = (const v4*)(Wfold + (size_t)j * UPS);
#pragma unroll
            for (int i = 0; i < UPS / 4; ++i) {
                v4 uv = u4[i], wv = wf4[i];
                acc += uv.x * wv.x + uv.y * wv.y + uv.z * wv.z + uv.w * wv.w;
            }
            float c = tanhf(acc + bcat2[j]);
            for (int i = tid; i < 64 * 26; i += 512) (&s_lg[0][0])[i] = 0.f;
            __syncthreads();
            const float* wo = WoutT + j * LGS;
            for (int v = 0; v < V; ++v) atomicAdd(&s_lg[lane][v], c * wo[v]);
            __syncthreads();
            float* dst = lgcur + bq * 64 * LGS;
            for (int i = tid; i < 64 * LGS; i += 512) {
                int v = i & 31;
                if (v < V) atomicAdd(&dst[i], s_lg[i >> 5][v]);
            }
        }
        grid_barrier(bar, ep++);
    }

    if (jb == 0) {
        const float* lr = logitsB + ((TS - 1) & 1) * (NB * LGS) + b * LGS;
        for (int v = w; v < V; v += 8)
            out[((size_t)b * V + v) * TS + (TS - 1)] = lr[v];
    }
}

extern "C" void kernel_launch(void* const* d_in, const int* in_sizes, int n_in,
                              void* d_out, int out_size, void* d_ws, size_t ws_size,
                              hipStream_t stream) {
    const float* latent = (const float*)d_in[0];
    const float* up     = (const float*)d_in[1];
    const float* embed  = (const float*)d_in[2];
    const float* W_hid  = (const float*)d_in[3];
    const float* b_hid  = (const float*)d_in[4];
    const float* W_ih   = (const float*)d_in[5];
    const float* b_ih   = (const float*)d_in[6];
    const float* W_hh   = (const float*)d_in[7];
    const float* b_hh   = (const float*)d_in[8];
    const float* W_mem  = (const float*)d_in[9];
    const float* b_mem  = (const float*)d_in[10];
    const float* W_cat  = (const float*)d_in[11];
    const float* b_cat  = (const float*)d_in[12];
    const float* W_out  = (const float*)d_in[13];
    const float* b_out  = (const float*)d_in[14];
    float* out = (float*)d_out;

    float* ws = (float*)d_ws;
    float* hB      = ws + OFF_HB;
    float* uctxB   = ws + OFF_UCTX;
    float* EgiT    = ws + OFF_EGI;
    float* Wfold   = ws + OFF_WFOLD;
    float* bcat2   = ws + OFF_BCAT2;
    float* WoutT   = ws + OFF_WOUTT;
    float* WmemT   = ws + OFF_WMEMT;
    float* logitsB = ws + OFF_LG;
    int*   bar     = (int*)(ws + OFF_BAR);

    k_init_egi<<<(V * 3 * H + 255) / 256, 256, 0, stream>>>(embed, W_ih, b_ih, EgiT);
    k_init_h0<<<NB, 512, 0, stream>>>(latent, W_hid, b_hid, hB);
    k_init_fold<<<(H * UPS + 255) / 256, 256, 0, stream>>>(W_cat, W_mem, Wfold);
    k_init_bcat<<<(H + 255) / 256, 256, 0, stream>>>(W_cat, b_mem, b_cat, bcat2);
    k_init_woutT<<<(H * LGS + 255) / 256, 256, 0, stream>>>(W_out, WoutT);
    k_init_wmemT<<<(UPS * H + 255) / 256, 256, 0, stream>>>(W_mem, WmemT);
    k_init_bar<<<1, 1024, 0, stream>>>(bar);

    k_main<<<NBLK, 512, 0, stream>>>(up, W_hh, b_hh, W_cat, b_out, out, hB, uctxB,
                                     EgiT, Wfold, bcat2, WoutT, WmemT, logitsB, bar);
}